// Round 2
// baseline (320.652 us; speedup 1.0000x reference)
//
#include <hip/hip_runtime.h>
#include <math.h>

#define KC 16
#define DF 256

// ws layout
#define WS_POOLED 0          // [16*256] S^T F accumulator (floats)
#define WS_CS     4096       // [16] cluster sizes
#define WS_M      4112       // [16] m_k = sum_e val*S[row][k]
#define WS_TR     4128       // trace accumulator
#define WS_ESUM   4129       // sum of edge_val (= 2*n_edges)
#define WS_TOTAL  4130
#define SHDW_OFF_BYTES 16640 // fp8 S shadow, 16 B/node, 16B-aligned

// NOTE: no __has_builtin / arch preprocessor gating here. Any such condition
// evaluates differently in the host (x86) vs device (amdgcn) compile pass and
// desynchronizes kernel selection (round-0 core dump: host launched a kernel
// whose device code was never emitted). gfx950 always has the fp8 cvt builtins.

typedef float floatx2 __attribute__((ext_vector_type(2)));

__global__ void zero_ws_kernel(float* __restrict__ ws) {
  int i = blockIdx.x * blockDim.x + threadIdx.x;
  if (i < WS_TOTAL) ws[i] = 0.0f;
}

// 16 fp8 (OCP e4m3fn) -> 16 f32 via 8 packed HW converts. Decode order matches
// the encode below (low half first), so a[k] corresponds to cluster k.
__device__ __forceinline__ void cvt16_fp8(uint4 u, float* f) {
  floatx2 p;
  p = __builtin_amdgcn_cvt_pk_f32_fp8(u.x, false); f[0] = p[0];  f[1] = p[1];
  p = __builtin_amdgcn_cvt_pk_f32_fp8(u.x, true);  f[2] = p[0];  f[3] = p[1];
  p = __builtin_amdgcn_cvt_pk_f32_fp8(u.y, false); f[4] = p[0];  f[5] = p[1];
  p = __builtin_amdgcn_cvt_pk_f32_fp8(u.y, true);  f[6] = p[0];  f[7] = p[1];
  p = __builtin_amdgcn_cvt_pk_f32_fp8(u.z, false); f[8] = p[0];  f[9] = p[1];
  p = __builtin_amdgcn_cvt_pk_f32_fp8(u.z, true);  f[10] = p[0]; f[11] = p[1];
  p = __builtin_amdgcn_cvt_pk_f32_fp8(u.w, false); f[12] = p[0]; f[13] = p[1];
  p = __builtin_amdgcn_cvt_pk_f32_fp8(u.w, true);  f[14] = p[0]; f[15] = p[1];
}

// ---------------------------------------------------------------------------
// assignments = softmax(F @ W + b) + cluster sizes + fp8 shadow of S.
// Thread-per-node; F staged transposed in LDS (stride 257); register
// double-buffer prefetch of the next 32-feature chunk hides global latency.
// ---------------------------------------------------------------------------
__global__ void __launch_bounds__(256) assign_kernel(
    const float* __restrict__ F, const float* __restrict__ W,
    const float* __restrict__ b, float* __restrict__ S,
    unsigned* __restrict__ Sh, float* __restrict__ ws, int n) {
  __shared__ float Ft[32 * 257];
  __shared__ float cs_l[KC];
  const int t = threadIdx.x;
  if (t < KC) cs_l[t] = 0.0f;
  const int nb = blockIdx.x << 8;
  const int node = nb + t;
  const bool valid = node < n;
  const bool interior = (nb + 256 <= n);

  const int nl = t >> 3;          // staged node within tile (per 'it' offset)
  const int jc = t & 7;           // float4 slot within 32-feature row

  float4 pref[8];
  auto load_chunk = [&](int s) {
    #pragma unroll
    for (int it = 0; it < 8; ++it) {
      const int nn = nl + (it << 5);
      if (interior || nb + nn < n)
        pref[it] = *(const float4*)&F[(size_t)(nb + nn) * DF + (s << 5) + (jc << 2)];
      else
        pref[it] = make_float4(0.f, 0.f, 0.f, 0.f);
    }
  };

  float acc[KC];
  #pragma unroll
  for (int k = 0; k < KC; ++k) acc[k] = 0.f;

  load_chunk(0);
  for (int s = 0; s < 8; ++s) {
    __syncthreads();               // previous compute done: LDS reusable
    #pragma unroll
    for (int it = 0; it < 8; ++it) {
      const int nn = nl + (it << 5);
      const int d0 = jc << 2;
      Ft[(d0 + 0) * 257 + nn] = pref[it].x;
      Ft[(d0 + 1) * 257 + nn] = pref[it].y;
      Ft[(d0 + 2) * 257 + nn] = pref[it].z;
      Ft[(d0 + 3) * 257 + nn] = pref[it].w;
    }
    __syncthreads();
    if (s < 7) load_chunk(s + 1);  // in flight during compute below
    #pragma unroll
    for (int j = 0; j < 8; ++j) {
      const float fv0 = Ft[(4 * j + 0) * 257 + t];
      const float fv1 = Ft[(4 * j + 1) * 257 + t];
      const float fv2 = Ft[(4 * j + 2) * 257 + t];
      const float fv3 = Ft[(4 * j + 3) * 257 + t];
      const float* __restrict__ Wg = &W[(size_t)((s << 5) + (j << 2)) * KC];
      #pragma unroll
      for (int k = 0; k < KC; ++k)
        acc[k] += fv0 * Wg[k] + fv1 * Wg[KC + k]
                + fv2 * Wg[2 * KC + k] + fv3 * Wg[3 * KC + k];
    }
  }

  // thread-local softmax
  float mx = -1e30f;
  #pragma unroll
  for (int k = 0; k < KC; ++k) { acc[k] += b[k]; mx = fmaxf(mx, acc[k]); }
  float sum = 0.f;
  #pragma unroll
  for (int k = 0; k < KC; ++k) { acc[k] = __expf(acc[k] - mx); sum += acc[k]; }
  const float inv = 1.0f / sum;
  #pragma unroll
  for (int k = 0; k < KC; ++k) acc[k] *= inv;
  if (!valid) {
    #pragma unroll
    for (int k = 0; k < KC; ++k) acc[k] = 0.f;
  }
  if (valid) {
    float4* __restrict__ So = (float4*)&S[(size_t)node * KC];
    So[0] = make_float4(acc[0],  acc[1],  acc[2],  acc[3]);
    So[1] = make_float4(acc[4],  acc[5],  acc[6],  acc[7]);
    So[2] = make_float4(acc[8],  acc[9],  acc[10], acc[11]);
    So[3] = make_float4(acc[12], acc[13], acc[14], acc[15]);
    if (Sh) {
      // pack 16 x fp8 e4m3fn (values in [0,1]; RNE, unbiased)
      unsigned w0, w1, w2, w3;
      w0 = __builtin_amdgcn_cvt_pk_fp8_f32(acc[0],  acc[1],  0,  false);
      w0 = __builtin_amdgcn_cvt_pk_fp8_f32(acc[2],  acc[3],  w0, true);
      w1 = __builtin_amdgcn_cvt_pk_fp8_f32(acc[4],  acc[5],  0,  false);
      w1 = __builtin_amdgcn_cvt_pk_fp8_f32(acc[6],  acc[7],  w1, true);
      w2 = __builtin_amdgcn_cvt_pk_fp8_f32(acc[8],  acc[9],  0,  false);
      w2 = __builtin_amdgcn_cvt_pk_fp8_f32(acc[10], acc[11], w2, true);
      w3 = __builtin_amdgcn_cvt_pk_fp8_f32(acc[12], acc[13], 0,  false);
      w3 = __builtin_amdgcn_cvt_pk_fp8_f32(acc[14], acc[15], w3, true);
      *(uint4*)&Sh[(size_t)node * 4] = make_uint4(w0, w1, w2, w3);
    }
  }
  // cluster sizes
  #pragma unroll
  for (int off = 1; off < 64; off <<= 1) {
    #pragma unroll
    for (int k = 0; k < KC; ++k) acc[k] += __shfl_xor(acc[k], off);
  }
  if ((t & 63) == 0) {
    #pragma unroll
    for (int k = 0; k < KC; ++k) atomicAdd(&cs_l[k], acc[k]);
  }
  __syncthreads();
  if (t < KC) atomicAdd(&ws[WS_CS + t], cs_l[t]);
}

// ---------------------------------------------------------------------------
// Edge pass (fp8 S): 8 edges/iter, ONE 16-B gather per endpoint (vs 2 for
// bf16) -> half the divergent-gather instructions and random L2 traffic.
// ---------------------------------------------------------------------------
__global__ void __launch_bounds__(256) edge_kernel_fp8(
    const int* __restrict__ erow, const int* __restrict__ ecol,
    const float* __restrict__ evl, const uint4* __restrict__ S8,
    float* __restrict__ ws, int ne) {
  __shared__ float red[KC + 2];
  const int t = threadIdx.x;
  if (t < KC + 2) red[t] = 0.0f;
  __syncthreads();

  float m[KC];
  #pragma unroll
  for (int i = 0; i < KC; ++i) m[i] = 0.f;
  float tr = 0.f, es = 0.f;

  const int tid = blockIdx.x * 256 + t;
  const int stride = gridDim.x * 256;
  for (int e0 = tid; e0 < ne; e0 += 8 * stride) {
    int r[8], c[8];
    float v[8];
    #pragma unroll
    for (int q = 0; q < 8; ++q) {
      const int e = e0 + q * stride;
      const bool ok = (q == 0) || (e < ne);
      r[q] = ok ? erow[e] : 0;
      c[q] = ok ? ecol[e] : 0;
      v[q] = ok ? evl[e] : 0.f;
    }
    uint4 A[8], B[8];
    #pragma unroll
    for (int q = 0; q < 8; ++q) { A[q] = S8[r[q]]; B[q] = S8[c[q]]; }
    #pragma unroll
    for (int q = 0; q < 8; ++q) {
      float a[16], bb[16];
      cvt16_fp8(A[q], a);
      cvt16_fp8(B[q], bb);
      float d = 0.f;
      #pragma unroll
      for (int k = 0; k < 16; ++k) d += a[k] * bb[k];
      tr += v[q] * d;
      es += v[q];
      #pragma unroll
      for (int k = 0; k < 16; ++k) m[k] += v[q] * a[k];
    }
  }
  #pragma unroll
  for (int off = 1; off < 64; off <<= 1) {
    tr += __shfl_xor(tr, off);
    es += __shfl_xor(es, off);
    #pragma unroll
    for (int i = 0; i < KC; ++i) m[i] += __shfl_xor(m[i], off);
  }
  if ((t & 63) == 0) {
    atomicAdd(&red[KC], tr);
    atomicAdd(&red[KC + 1], es);
    #pragma unroll
    for (int i = 0; i < KC; ++i) atomicAdd(&red[i], m[i]);
  }
  __syncthreads();
  if (t < KC)            atomicAdd(&ws[WS_M + t], red[t]);
  else if (t == KC)      atomicAdd(&ws[WS_TR], red[KC]);
  else if (t == KC + 1)  atomicAdd(&ws[WS_ESUM], red[KC + 1]);
}

// fp32 fallback (ws too small for the fp8 shadow) — runtime choice, host and
// device always agree (both kernels always compiled).
__global__ void __launch_bounds__(256) edge_kernel_f32(
    const int* __restrict__ erow, const int* __restrict__ ecol,
    const float* __restrict__ evl, const float* __restrict__ S,
    float* __restrict__ ws, int ne) {
  __shared__ float red[KC + 2];
  const int t = threadIdx.x;
  if (t < KC + 2) red[t] = 0.0f;
  __syncthreads();
  float m[KC];
  #pragma unroll
  for (int i = 0; i < KC; ++i) m[i] = 0.f;
  float tr = 0.f, es = 0.f;
  const int stride = gridDim.x * blockDim.x;
  for (int e = blockIdx.x * blockDim.x + t; e < ne; e += stride) {
    const int r = erow[e];
    const int c = ecol[e];
    const float v = evl[e];
    const float4* __restrict__ Sr = (const float4*)(S + (size_t)r * KC);
    const float4* __restrict__ Sc = (const float4*)(S + (size_t)c * KC);
    const float4 a0 = Sr[0], a1 = Sr[1], a2 = Sr[2], a3 = Sr[3];
    const float4 b0 = Sc[0], b1 = Sc[1], b2 = Sc[2], b3 = Sc[3];
    float d = a0.x*b0.x + a0.y*b0.y + a0.z*b0.z + a0.w*b0.w
            + a1.x*b1.x + a1.y*b1.y + a1.z*b1.z + a1.w*b1.w
            + a2.x*b2.x + a2.y*b2.y + a2.z*b2.z + a2.w*b2.w
            + a3.x*b3.x + a3.y*b3.y + a3.z*b3.z + a3.w*b3.w;
    tr += v * d; es += v;
    m[0]+=v*a0.x; m[1]+=v*a0.y; m[2]+=v*a0.z; m[3]+=v*a0.w;
    m[4]+=v*a1.x; m[5]+=v*a1.y; m[6]+=v*a1.z; m[7]+=v*a1.w;
    m[8]+=v*a2.x; m[9]+=v*a2.y; m[10]+=v*a2.z; m[11]+=v*a2.w;
    m[12]+=v*a3.x; m[13]+=v*a3.y; m[14]+=v*a3.z; m[15]+=v*a3.w;
  }
  #pragma unroll
  for (int off = 1; off < 64; off <<= 1) {
    tr += __shfl_xor(tr, off);
    es += __shfl_xor(es, off);
    #pragma unroll
    for (int i = 0; i < KC; ++i) m[i] += __shfl_xor(m[i], off);
  }
  if ((t & 63) == 0) {
    atomicAdd(&red[KC], tr);
    atomicAdd(&red[KC + 1], es);
    #pragma unroll
    for (int i = 0; i < KC; ++i) atomicAdd(&red[i], m[i]);
  }
  __syncthreads();
  if (t < KC)            atomicAdd(&ws[WS_M + t], red[t]);
  else if (t == KC)      atomicAdd(&ws[WS_TR], red[KC]);
  else if (t == KC + 1)  atomicAdd(&ws[WS_ESUM], red[KC + 1]);
}

// ---------------------------------------------------------------------------
// pooled = S^T @ F. Thread owns feature column t; 32 register-staged F loads
// per chunk before the FMA block; S rows are uniform -> scalar loads.
// ---------------------------------------------------------------------------
__global__ void __launch_bounds__(256) pool_kernel(
    const float* __restrict__ F, const float* __restrict__ S,
    float* __restrict__ ws, int n) {
  const int t = threadIdx.x;
  float acc[KC];
  #pragma unroll
  for (int i = 0; i < KC; ++i) acc[i] = 0.f;

  const int nch = n >> 5;
  for (int ch = blockIdx.x; ch < nch; ch += gridDim.x) {
    const int base = ch << 5;
    float fl[32];
    #pragma unroll
    for (int i = 0; i < 32; ++i)
      fl[i] = F[(size_t)(base + i) * DF + t];
    #pragma unroll
    for (int i = 0; i < 32; ++i) {
      const float4* __restrict__ Sr = (const float4*)(S + (size_t)(base + i) * KC);
      const float4 s0 = Sr[0], s1 = Sr[1], s2 = Sr[2], s3 = Sr[3];
      const float f = fl[i];
      acc[0]+=f*s0.x;  acc[1]+=f*s0.y;  acc[2]+=f*s0.z;  acc[3]+=f*s0.w;
      acc[4]+=f*s1.x;  acc[5]+=f*s1.y;  acc[6]+=f*s1.z;  acc[7]+=f*s1.w;
      acc[8]+=f*s2.x;  acc[9]+=f*s2.y;  acc[10]+=f*s2.z; acc[11]+=f*s2.w;
      acc[12]+=f*s3.x; acc[13]+=f*s3.y; acc[14]+=f*s3.z; acc[15]+=f*s3.w;
    }
  }
  if (blockIdx.x == 0) {                 // tail (n % 32)
    for (int i2 = nch << 5; i2 < n; ++i2) {
      const float f = F[(size_t)i2 * DF + t];
      const float* __restrict__ Sr = S + (size_t)i2 * KC;
      #pragma unroll
      for (int kk = 0; kk < KC; ++kk) acc[kk] += f * Sr[kk];
    }
  }
  #pragma unroll
  for (int kk = 0; kk < KC; ++kk)
    atomicAdd(&ws[WS_POOLED + kk * DF + t], acc[kk]);
}

__global__ void finalize_kernel(const float* __restrict__ ws,
                                float* __restrict__ out, int n) {
  const int t = threadIdx.x;
  const float alpha = 1.6732632423543772f;
  const float scale = 1.0507009873554805f;
  for (int idx = t; idx < KC * DF; idx += blockDim.x) {
    const int k = idx >> 8;
    const float x = ws[WS_POOLED + idx] / ws[WS_CS + k];
    const float r = x > 0.f ? x : alpha * expm1f(x);
    out[idx] = scale * r;
  }
  if (t == 0) {
    const float esum = ws[WS_ESUM];   // = 2 * n_edges
    const float tr = ws[WS_TR];
    float sm2 = 0.f, sc2 = 0.f;
    for (int i = 0; i < KC; ++i) {
      const float mi = ws[WS_M + i];
      sm2 += mi * mi;
      const float ci = ws[WS_CS + i];
      sc2 += ci * ci;
    }
    const float spectral = -(tr - sm2 / esum) / esum;
    const float collapse = 0.1f * (sqrtf(sc2) / (float)n * 4.0f - 1.0f);
    const size_t off = (size_t)(KC * DF) + (size_t)n * KC;
    out[off] = spectral;
    out[off + 1] = collapse;
  }
}

extern "C" void kernel_launch(void* const* d_in, const int* in_sizes, int n_in,
                              void* d_out, int out_size, void* d_ws, size_t ws_size,
                              hipStream_t stream) {
  const float* F   = (const float*)d_in[0];
  const float* W   = (const float*)d_in[1];
  const float* b   = (const float*)d_in[2];
  const int* erow  = (const int*)d_in[3];
  const int* ecol  = (const int*)d_in[4];
  const float* evl = (const float*)d_in[5];
  const int n  = in_sizes[0] / DF;
  const int ne = in_sizes[3];
  float* out = (float*)d_out;
  float* S   = out + KC * DF;      // assignments live directly in d_out
  float* ws  = (float*)d_ws;

  const size_t shadow_bytes = (size_t)n * 16;   // fp8: 16 B/node
  const bool use_shadow = ws_size >= (size_t)SHDW_OFF_BYTES + shadow_bytes + 64;
  unsigned* Sh = use_shadow ? (unsigned*)((char*)d_ws + SHDW_OFF_BYTES) : nullptr;

  zero_ws_kernel<<<(WS_TOTAL + 255) / 256, 256, 0, stream>>>(ws);
  assign_kernel<<<(n + 255) / 256, 256, 0, stream>>>(F, W, b, S, Sh, ws, n);
  if (use_shadow)
    edge_kernel_fp8<<<1024, 256, 0, stream>>>(erow, ecol, evl, (const uint4*)Sh, ws, ne);
  else
    edge_kernel_f32<<<2048, 256, 0, stream>>>(erow, ecol, evl, S, ws, ne);
  pool_kernel<<<1024, 256, 0, stream>>>(F, S, ws, n);
  finalize_kernel<<<1, 256, 0, stream>>>(ws, out, n);
}